// Round 3
// baseline (143.975 us; speedup 1.0000x reference)
//
#include <hip/hip_runtime.h>

// BinLinear: C = input @ binarize(weight),  binarize(w) = (w>=0 ? +1 : -1)
// Identity:  C[n][o] = rowsum(A[n]) - 2 * sum_{i: w[i][o] < 0} A[n][i]
//
// SINGLE fused dispatch (1280 blocks):
//   blocks 0..255    : scan W -> negbits[64][2048] sign masks, publish
//                      done[b] = MAGIC | blockDirty  (release, device scope)
//   blocks 256..1279 : 2 rows per wave: load A row, shfl reduce (independent
//                      of scan -> overlaps it), THEN poll done[] (acquire),
//                      broadcast rowsum (clean) or exact bitmask-gather fixup
//                      (dirty; never hit for U[0,1) weights).
// Deadlock-safe by capacity: __launch_bounds__(256,5) => >=5 blocks/CU =>
// all 1280 blocks co-resident regardless of dispatch order.
// Poison-safe: 0xAAAAAAAA never matches MAGIC. Stale-MAGIC-safe: republished
// values are identical every call (deterministic), so early readers are fine.

constexpr int NROWS  = 8192;
constexpr int K      = 2048;
constexpr int NOP    = 2048;
constexpr int GROUPS = K / 32;           // 64 u32 sign-words per column
constexpr int NSCAN  = 256;              // scan blocks
constexpr int NROWB  = 1024;             // row blocks (4 waves x 2 rows = 8 rows)
constexpr unsigned MAGIC = 0x51C0DE00u;  // published: (done & ~1u) == MAGIC

// ws layout: [0,1KB) u32 done[256]; [1KB, 1KB+512KB) u32 negbits[64][2048]

__device__ __forceinline__ float wave_sum(float s) {
    #pragma unroll
    for (int m = 32; m >= 1; m >>= 1) s += __shfl_xor(s, m, 64);
    return s;
}

// Exact correction for a dirty column o: sum of A[n][i] over negative rows i.
__device__ float neg_corr(const float* __restrict__ arow,
                          const unsigned* __restrict__ negbits, int o) {
    float c = 0.0f;
    for (int g = 0; g < GROUPS; ++g) {
        unsigned wd = negbits[(size_t)g * NOP + o];
        while (wd) { int b = __ffs(wd) - 1; c += arow[g * 32 + b]; wd &= wd - 1; }
    }
    return c;
}

__global__ __launch_bounds__(256, 5) void fused(
        const float* __restrict__ a, const float* __restrict__ w,
        float* __restrict__ out, unsigned* __restrict__ done,
        unsigned* __restrict__ negbits) {
    const int lane = threadIdx.x & 63;
    const int wid  = threadIdx.x >> 6;

    if (blockIdx.x < NSCAN) {
        // ---------------- scan W ----------------
        const int b   = blockIdx.x;
        const int col = (b & 7) * 256 + threadIdx.x;   // 8 col-blocks
        const int g0  = (b >> 3) * 2;                  // 32 group-pairs
        unsigned any = 0u;
        #pragma unroll
        for (int gg = 0; gg < 2; ++gg) {
            const int g = g0 + gg;
            const float* p = w + (size_t)(g * 32) * NOP + col;
            unsigned word = 0u;
            #pragma unroll
            for (int r = 0; r < 32; ++r) {
                float v = p[(size_t)r * NOP];
                // -1 iff !(tanh(v)>=0) iff !(v>=0): NaN -> -1, -0.0 -> +1
                if (!(v >= 0.0f)) word |= (1u << r);
            }
            negbits[(size_t)g * NOP + col] = word;     // coalesced 256B store
            any |= word;
        }
        __shared__ int wd4[4];
        const int aw = __any(any != 0u) ? 1 : 0;
        if (lane == 0) wd4[wid] = aw;
        __syncthreads();   // also drains this block's negbits stores (vmcnt 0)
        if (threadIdx.x == 0) {
            const unsigned flag = (unsigned)(wd4[0] | wd4[1] | wd4[2] | wd4[3]);
            __hip_atomic_store(&done[b], MAGIC | flag,
                               __ATOMIC_RELEASE, __HIP_MEMORY_SCOPE_AGENT);
        }
        return;
    }

    // ---------------- rows (2 per wave) ----------------
    const int rb = blockIdx.x - NSCAN;
    const int n0 = (rb * 4 + wid) * 2;
    const float4* __restrict__ a40 = (const float4*)(a + (size_t)n0 * K);
    const float4* __restrict__ a41 = (const float4*)(a + (size_t)(n0 + 1) * K);

    float4 u[8], v[8];
    #pragma unroll
    for (int c = 0; c < 8; ++c) { u[c] = a40[c * 64 + lane];
                                  v[c] = a41[c * 64 + lane]; }
    float s0 = 0.f, s1 = 0.f;
    #pragma unroll
    for (int c = 0; c < 8; ++c) {
        s0 += (u[c].x + u[c].y) + (u[c].z + u[c].w);
        s1 += (v[c].x + v[c].y) + (v[c].z + v[c].w);
    }
    s0 = wave_sum(s0);
    s1 = wave_sum(s1);

    // ---- wait for scan publish (usually already done by now) ----
    unsigned orv;
    for (;;) {
        bool ok = true; orv = 0u;
        #pragma unroll
        for (int j = 0; j < 4; ++j) {
            const unsigned d = __hip_atomic_load(&done[lane * 4 + j],
                    __ATOMIC_ACQUIRE, __HIP_MEMORY_SCOPE_AGENT);
            ok &= ((d & ~1u) == MAGIC);
            orv |= d;
        }
        if (__all(ok)) break;
        __builtin_amdgcn_s_sleep(8);
    }
    const bool dirty = __any((orv & 1u) != 0u);

    float4* __restrict__ o40 = (float4*)(out + (size_t)n0 * NOP);
    float4* __restrict__ o41 = (float4*)(out + (size_t)(n0 + 1) * NOP);
    if (!dirty) {
        const float4 r0 = make_float4(s0, s0, s0, s0);
        const float4 r1 = make_float4(s1, s1, s1, s1);
        #pragma unroll
        for (int c = 0; c < 8; ++c) { o40[c * 64 + lane] = r0;
                                      o41[c * 64 + lane] = r1; }
    } else {
        __threadfence();   // acquire visibility for negbits from all scan blocks
        const float* __restrict__ arow0 = a + (size_t)n0 * K;
        const float* __restrict__ arow1 = a + (size_t)(n0 + 1) * K;
        #pragma unroll 1
        for (int c = 0; c < 8; ++c) {
            const int ob = (c * 64 + lane) * 4;
            float r0[4], r1[4];
            #pragma unroll 1
            for (int j = 0; j < 4; ++j) {
                r0[j] = s0 - 2.0f * neg_corr(arow0, negbits, ob + j);
                r1[j] = s1 - 2.0f * neg_corr(arow1, negbits, ob + j);
            }
            o40[c * 64 + lane] = make_float4(r0[0], r0[1], r0[2], r0[3]);
            o41[c * 64 + lane] = make_float4(r1[0], r1[1], r1[2], r1[3]);
        }
    }
}

extern "C" void kernel_launch(void* const* d_in, const int* in_sizes, int n_in,
                              void* d_out, int out_size, void* d_ws, size_t ws_size,
                              hipStream_t stream) {
    const float* a = (const float*)d_in[0];   // input  [8192, 2048]
    const float* w = (const float*)d_in[1];   // weight [2048, 2048]
    float* out = (float*)d_out;               // [8192, 2048]

    unsigned* done    = (unsigned*)d_ws;
    unsigned* negbits = (unsigned*)((char*)d_ws + 1024);

    fused<<<dim3(NSCAN + NROWB), dim3(256), 0, stream>>>(
        a, w, out, done, negbits);
}

// Round 4
// 29.127 us; speedup vs baseline: 4.9431x; 4.9431x over previous
//
#include <hip/hip_runtime.h>

// BinLinear: C = input @ binarize(weight),  binarize(w) = (w>=0 ? +1 : -1)
// Identity:  C[n][o] = rowsum(A[n]) - 2 * sum_{i: w[i][o] < 0} A[n][i]
//
// Two dependency-free pure-stream dispatches (no atomics, no polling —
// round-3's per-wave agent-scope acquire caused a buffer_inv storm):
//   D1 prep  : 512 scan blocks  (read W 16 MB -> packed sign masks + dirty)
//              2048 rowsum blocks (read A 64 MB -> rowsum[8192])
//              uniform 32 KB/block, ~80 MB reads, 0.55 MB writes.
//   D2 writeC: wave-per-row; clean path reads ONLY rowsum[n] (4 B) + 512 B
//              dirty flags (L2-hot) then broadcast-stores the row -> a pure
//              64 MB write stream at fill-kernel BW. Dirty columns take the
//              exact bitmask-gather fixup (never hit for U[0,1) weights).

constexpr int NROWS = 8192;
constexpr int K     = 2048;
constexpr int NOP   = 2048;
constexpr int NSCAN = 512;            // scan blocks
constexpr int NSUM  = 2048;           // rowsum blocks (4 rows each)
constexpr int GRPS  = K / 8;          // 256 groups of 8 rows
constexpr int C4    = NOP / 4;        // 512 packed-col words per group

// ws layout (all fully written by D1 every call):
//   [0,    512)  : u8   dirty[512]        (per-scan-block any-negative flag)
//   [1024, 33792): f32  rowsum[8192]
//   [36864, +512K): u32 negbits[256][512] (byte j of word = col 4c+j mask, 8 rows)

__global__ __launch_bounds__(256) void prep(
        const float* __restrict__ a, const float* __restrict__ w,
        unsigned char* __restrict__ dirty, float* __restrict__ rowsum,
        unsigned* __restrict__ negbits) {
    const int lane = threadIdx.x & 63;
    const int wid  = threadIdx.x >> 6;

    if (blockIdx.x < NSCAN) {
        // ---- scan W: this block covers cols [colb*1024, +1024) x 8 rows ----
        const int b    = blockIdx.x;
        const int colb = b & 1;
        const int grp  = b >> 1;                    // 8-row group
        const int c4   = colb * 256 + threadIdx.x;  // packed col word index
        const float4* __restrict__ w4 =
            (const float4*)(w + (size_t)(grp * 8) * NOP + c4 * 4);

        unsigned packed = 0u;
        #pragma unroll
        for (int r = 0; r < 8; ++r) {
            const float4 v = w4[r * (NOP / 4)];
            // -1 iff !(tanh(x)>=0) iff !(x>=0): NaN -> -1, -0.0 -> +1
            if (!(v.x >= 0.0f)) packed |= (1u << r);
            if (!(v.y >= 0.0f)) packed |= (1u << (8 + r));
            if (!(v.z >= 0.0f)) packed |= (1u << (16 + r));
            if (!(v.w >= 0.0f)) packed |= (1u << (24 + r));
        }
        negbits[(size_t)grp * C4 + c4] = packed;    // coalesced 1 KB store

        __shared__ int wd4[4];
        const int aw = __any(packed != 0u) ? 1 : 0;
        if (lane == 0) wd4[wid] = aw;
        __syncthreads();
        if (threadIdx.x == 0)
            dirty[b] = (unsigned char)(wd4[0] | wd4[1] | wd4[2] | wd4[3]);
        return;
    }

    // ---- rowsum: wave per row, 4 rows per block ----
    const int n = (blockIdx.x - NSCAN) * 4 + wid;
    const float4* __restrict__ a4 = (const float4*)(a + (size_t)n * K);
    float4 v[8];
    #pragma unroll
    for (int c = 0; c < 8; ++c) v[c] = a4[c * 64 + lane];
    float s = 0.0f;
    #pragma unroll
    for (int c = 0; c < 8; ++c) s += (v[c].x + v[c].y) + (v[c].z + v[c].w);
    #pragma unroll
    for (int m = 32; m >= 1; m >>= 1) s += __shfl_xor(s, m, 64);
    if (lane == 0) rowsum[n] = s;
}

// Exact correction for a dirty column o (slow path; unused for clean W).
__device__ float neg_corr(const float* __restrict__ arow,
                          const unsigned* __restrict__ negbits, int o) {
    float c = 0.0f;
    const int cw = o >> 2, sh = (o & 3) * 8;
    for (int g = 0; g < GRPS; ++g) {
        unsigned m = (negbits[(size_t)g * C4 + cw] >> sh) & 0xFFu;
        while (m) { int b = __ffs(m) - 1; c += arow[g * 8 + b]; m &= m - 1; }
    }
    return c;
}

__global__ __launch_bounds__(256) void writeC(
        const float* __restrict__ a,
        const unsigned long long* __restrict__ dirty8,
        const float* __restrict__ rowsum,
        const unsigned* __restrict__ negbits,
        float* __restrict__ out) {
    const int lane = threadIdx.x & 63;
    const int wid  = threadIdx.x >> 6;
    const int n    = blockIdx.x * 4 + wid;

    const float s = rowsum[n];                       // uniform 4 B (L2-hot)
    const unsigned long long dv = dirty8[lane];      // 512 B flags (L2-hot)
    const bool dirty = __any(dv != 0ull);

    float4* __restrict__ o4 = (float4*)(out + (size_t)n * NOP);
    if (!dirty) {
        const float4 rv = make_float4(s, s, s, s);
        #pragma unroll
        for (int c = 0; c < 8; ++c) o4[c * 64 + lane] = rv;  // pure 8 KB stream
    } else {
        const float* __restrict__ arow = a + (size_t)n * K;
        #pragma unroll 1
        for (int c = 0; c < 8; ++c) {
            const int ob = (c * 64 + lane) * 4;
            float r[4];
            #pragma unroll 1
            for (int j = 0; j < 4; ++j)
                r[j] = s - 2.0f * neg_corr(arow, negbits, ob + j);
            o4[c * 64 + lane] = make_float4(r[0], r[1], r[2], r[3]);
        }
    }
}

extern "C" void kernel_launch(void* const* d_in, const int* in_sizes, int n_in,
                              void* d_out, int out_size, void* d_ws, size_t ws_size,
                              hipStream_t stream) {
    const float* a = (const float*)d_in[0];   // input  [8192, 2048]
    const float* w = (const float*)d_in[1];   // weight [2048, 2048]
    float* out = (float*)d_out;               // [8192, 2048]

    unsigned char* dirty = (unsigned char*)d_ws;
    float*    rowsum  = (float*)((char*)d_ws + 1024);
    unsigned* negbits = (unsigned*)((char*)d_ws + 36864);

    prep<<<dim3(NSCAN + NSUM), dim3(256), 0, stream>>>(
        a, w, dirty, rowsum, negbits);

    writeC<<<dim3(NROWS / 4), dim3(256), 0, stream>>>(
        a, (const unsigned long long*)dirty, rowsum, negbits, out);
}

// Round 5
// 28.489 us; speedup vs baseline: 5.0538x; 1.0224x over previous
//
#include <hip/hip_runtime.h>

// BinLinear: C = input @ binarize(weight),  binarize(w) = (w>=0 ? +1 : -1)
// Identity:  C[n][o] = rowsum(A[n]) - 2 * sum_{i: w[i][o] < 0} A[n][i]
//
// Speculative overlap, 2 dispatches, no atomics / polling / cross-block sync:
//   D1 fused_spec (2560 blocks):
//     blocks 0..511    : scan W (16 MB) -> negbits sign masks + dirty[512]
//     blocks 512..2559 : wave-per-row: read A row (8 KB), shfl rowsum,
//                        store rowsum[n], SPECULATIVELY write C row =
//                        rowsum broadcast (nt stores). All three streams
//                        (W-read, A-read, C-write) run concurrently.
//   D2 fixup (256 blocks): read 512 B dirty flags (L2-hot), early-exit when
//     clean (always, for U[0,1) weights). Dirty: overwrite affected C rows
//     exactly from rowsum + negbits (no RMW -> speculative values never used).
// Kernel-boundary ordering is the only synchronization.

typedef float f32x4 __attribute__((ext_vector_type(4)));

constexpr int NROWS = 8192;
constexpr int K     = 2048;
constexpr int NOP   = 2048;
constexpr int NSCAN = 512;            // scan blocks in D1
constexpr int GRPS  = K / 8;          // 256 groups of 8 rows
constexpr int C4    = NOP / 4;        // 512 packed-col words per group

// ws layout (all fully written by D1 every call):
//   [0,    512)   : u8   dirty[512]
//   [1024, 33792) : f32  rowsum[8192]
//   [36864,+512K) : u32  negbits[256][512] (byte j = col 4c+j, bits = 8 rows)

__global__ __launch_bounds__(256) void fused_spec(
        const float* __restrict__ a, const float* __restrict__ w,
        unsigned char* __restrict__ dirty, float* __restrict__ rowsum,
        unsigned* __restrict__ negbits, float* __restrict__ out) {
    const int lane = threadIdx.x & 63;
    const int wid  = threadIdx.x >> 6;

    if (blockIdx.x < NSCAN) {
        // ---- scan W: block covers 1024 cols x 8 rows (32 KB) ----
        const int b    = blockIdx.x;
        const int colb = b & 1;
        const int grp  = b >> 1;                    // 8-row group
        const int c4   = colb * 256 + threadIdx.x;  // packed col-word index
        const f32x4* __restrict__ w4 =
            (const f32x4*)(w + (size_t)(grp * 8) * NOP + c4 * 4);

        unsigned packed = 0u;
        #pragma unroll
        for (int r = 0; r < 8; ++r) {
            const f32x4 v = w4[(size_t)r * (NOP / 4)];
            // -1 iff !(tanh(x)>=0) iff !(x>=0): NaN -> -1, -0.0 -> +1
            if (!(v.x >= 0.0f)) packed |= (1u << r);
            if (!(v.y >= 0.0f)) packed |= (1u << (8 + r));
            if (!(v.z >= 0.0f)) packed |= (1u << (16 + r));
            if (!(v.w >= 0.0f)) packed |= (1u << (24 + r));
        }
        __builtin_nontemporal_store(packed, &negbits[(size_t)grp * C4 + c4]);

        __shared__ int wd4[4];
        const int aw = __any(packed != 0u) ? 1 : 0;
        if (lane == 0) wd4[wid] = aw;
        __syncthreads();
        if (threadIdx.x == 0)
            dirty[b] = (unsigned char)(wd4[0] | wd4[1] | wd4[2] | wd4[3]);
        return;
    }

    // ---- wave per row: rowsum + speculative C broadcast ----
    const int n = (blockIdx.x - NSCAN) * 4 + wid;
    const f32x4* __restrict__ a4 = (const f32x4*)(a + (size_t)n * K);
    f32x4 v[8];
    #pragma unroll
    for (int c = 0; c < 8; ++c) v[c] = a4[c * 64 + lane];
    float s = 0.0f;
    #pragma unroll
    for (int c = 0; c < 8; ++c) s += (v[c].x + v[c].y) + (v[c].z + v[c].w);
    #pragma unroll
    for (int m = 32; m >= 1; m >>= 1) s += __shfl_xor(s, m, 64);
    if (lane == 0) rowsum[n] = s;

    const f32x4 rv = {s, s, s, s};
    f32x4* __restrict__ o4 = (f32x4*)(out + (size_t)n * NOP);
    #pragma unroll
    for (int c = 0; c < 8; ++c)
        __builtin_nontemporal_store(rv, &o4[c * 64 + lane]);
}

// Exact correction for a dirty column o (slow path; unused for clean W).
__device__ float neg_corr(const float* __restrict__ arow,
                          const unsigned* __restrict__ negbits, int o) {
    float c = 0.0f;
    const int cw = o >> 2, sh = (o & 3) * 8;
    for (int g = 0; g < GRPS; ++g) {
        unsigned m = (negbits[(size_t)g * C4 + cw] >> sh) & 0xFFu;
        while (m) { int b = __ffs(m) - 1; c += arow[g * 8 + b]; m &= m - 1; }
    }
    return c;
}

__global__ __launch_bounds__(256) void fixup(
        const float* __restrict__ a,
        const unsigned long long* __restrict__ dirty8,
        const float* __restrict__ rowsum,
        const unsigned* __restrict__ negbits,
        float* __restrict__ out) {
    const int lane = threadIdx.x & 63;
    const unsigned long long dv = dirty8[lane];   // 64 x 8 B = all 512 flags
    if (!__any(dv != 0ull)) return;               // clean: ~free

    // dirty: overwrite this block's 32 rows exactly (never hit for U[0,1))
    for (int r = 0; r < 32; ++r) {
        const int n = blockIdx.x * 32 + r;
        const float s = rowsum[n];
        const float* __restrict__ arow = a + (size_t)n * K;
        for (int o = threadIdx.x; o < NOP; o += 256)
            out[(size_t)n * NOP + o] = s - 2.0f * neg_corr(arow, negbits, o);
    }
}

extern "C" void kernel_launch(void* const* d_in, const int* in_sizes, int n_in,
                              void* d_out, int out_size, void* d_ws, size_t ws_size,
                              hipStream_t stream) {
    const float* a = (const float*)d_in[0];   // input  [8192, 2048]
    const float* w = (const float*)d_in[1];   // weight [2048, 2048]
    float* out = (float*)d_out;               // [8192, 2048]

    unsigned char* dirty = (unsigned char*)d_ws;
    float*    rowsum  = (float*)((char*)d_ws + 1024);
    unsigned* negbits = (unsigned*)((char*)d_ws + 36864);

    fused_spec<<<dim3(NSCAN + NROWS / 4), dim3(256), 0, stream>>>(
        a, w, dirty, rowsum, negbits, out);

    fixup<<<dim3(256), dim3(256), 0, stream>>>(
        a, (const unsigned long long*)dirty, rowsum, negbits, out);
}